// Round 6
// baseline (306.901 us; speedup 1.0000x reference)
//
#include <hip/hip_runtime.h>

#define SEQ    256
#define FEAT   768
#define FILT   6
#define WELEMS (2304 * FILT)       // 13824 floats per s

#define QS     4                   // s-outputs per block (quad)
#define NROW   6                   // x rows per quad: s0-1 .. s0+4
#define TPK    6                   // K-steps per band per kv-slice (24/4)
#define DEPTH  6                   // prefetch queue depth (K-steps)

typedef _Float16 f16x8 __attribute__((ext_vector_type(8)));  // MFMA A/B frag
typedef __attribute__((ext_vector_type(4))) float f32x4;     // MFMA C/D

// R11: s-quad row sharing. R9 (ILP) and R10 (TLP) both null at ~100-105us
// => binding resource is LOGICAL global-load bytes: 3x-read x + W = 647MB
// / 100us = 6.5 TB/s = the measured global_load service ceiling (~10
// B/cyc/CU), independent of L2/L3 hit level. Fix: block owns an s-QUAD
// (4 outputs) x 64 batches; each wave loads a row chunk ONCE and MFMAs it
// into up to 3 s-accumulators (band w = rho - sv) from 3 W[s] LDS tables.
// 6 rows / 4 outputs = 1.5 rows/output vs 3 -> logical loads 647 -> 352MB
// -> 54us floor. Grid 256 = 64 quads x 4 batch-quarters; 1024 thr = 16
// waves = (mt 0..3) x (K-split kv 0..3) -> 4 waves/SIMD (R10 proved more
// adds nothing). K-merge: 3-round LDS tree (32KB), 3 barriers, once per
// kernel. Row-end barriers (6) keep the 4 quarter-blocks of a quad
// L2-coincident; swizzle puts them on one XCD (s in [32*xcd, 32*xcd+32)).
// Kept from R7-R10: mfma_f32_16x16x32_f16 with 2-term exact f16 split of
// x, W RTN once at staging; A/B share the (h,e)->k bijection; C/D
// col=lane&15, row=4*(lane>>4)+reg (HW-verified); col>=6 lanes clamp B
// addr (garbage only in never-stored D cols); depth-6 circular prefetch
// crossing row barriers (next row's 12 loads in flight at each barrier).
__global__ __launch_bounds__(1024, 4)
void pos_linear_kernel(const float* __restrict__ x,
                       const float* __restrict__ W,
                       const float* __restrict__ bias,
                       float* __restrict__ out) {
    __shared__ __align__(16) unsigned short wf[QS * 13824];  // 108 KB f16 frags
    __shared__ float red[2][4096];                           // 32 KB K-merge

    const int blk  = blockIdx.x;
    const int xcd  = blk & 7;                 // dispatch round-robin XCD
    const int idx  = blk >> 3;                // 0..31 within XCD
    const int quad = 8 * xcd + (idx & 7);     // 0..63, s-contiguous per XCD
    const int bq   = idx >> 3;                // batch quarter 0..3 (same XCD)
    const int s0   = 4 * quad;
    const int tid  = threadIdx.x;

    // ---- Stage W[s0..s0+3] -> f16 fragments in LDS (one-time, RTN) ----
    // frag short idx within table: ((k>>3)*6 + o)*8 + (k&7), k = 32T+8h+e.
    #pragma unroll
    for (int sv = 0; sv < QS; ++sv) {
        const float* Ws = W + (size_t)(s0 + sv) * WELEMS;
        unsigned short* wt = wf + sv * 13824;
        for (int k = tid; k < 2304; k += 1024) {
            const int slot8 = (k >> 3) * 6;
            const int e     = k & 7;
            #pragma unroll
            for (int o = 0; o < FILT; ++o) {
                _Float16 hv = (_Float16)Ws[k * FILT + o];
                wt[(slot8 + o) * 8 + e] = *(const unsigned short*)&hv;
            }
        }
    }
    __syncthreads();

    const int lane = tid & 63;
    const int wave = tid >> 6;      // 0..15
    const int mt   = wave >> 2;     // 16-batch tile 0..3
    const int kv   = wave & 3;      // K-slice 0..3
    const int rowm = lane & 15;     // batch within tile (A side)
    const int h    = lane >> 4;     // k-group 0..3
    const int col  = lane & 15;     // output col (valid < 6, B side)
    const bool cv  = col < FILT;
    const int b0   = bq * 64 + mt * 16;

    // B-frag short base: (6h+c)*8 + 1152*kv  (T = 24w + 6kv + tloc;
    // 192*T = 4608w + 1152kv + 192tloc; w,tloc folded as immediates).
    const int bidx = (6 * h + (cv ? col : 5)) * 8 + 1152 * kv;

    f32x4 acc_h[QS], acc_l[QS];
    #pragma unroll
    for (int sv = 0; sv < QS; ++sv) {
        acc_h[sv] = (f32x4){0.f, 0.f, 0.f, 0.f};
        acc_l[sv] = (f32x4){0.f, 0.f, 0.f, 0.f};
    }

    // per-lane x base: batch (b0+rowm), feature 8h, kv K-window 192*kv floats
    const float* xb = x + (size_t)(b0 + rowm) * (SEQ * FEAT) + 8 * h + 192 * kv;
    const f32x4* rp[NROW];
    bool rv[NROW];
    #pragma unroll
    for (int q = 0; q < NROW; ++q) {
        const int r = s0 - 1 + q;
        rv[q] = (r >= 0) && (r < SEQ);
        rp[q] = (const f32x4*)(xb + (size_t)(rv[q] ? r : 0) * FEAT);
    }

    // ---- main stream: 6 rows x 6 K-steps, depth-6 circular prefetch ----
    f32x4 qa[DEPTH], qb[DEPTH];
    #pragma unroll
    for (int g = 0; g < DEPTH; ++g) {          // prologue: all of row 0
        qa[g] = rp[0][8 * g];
        qb[g] = rp[0][8 * g + 1];
    }

    #pragma unroll
    for (int g = 0; g < NROW * TPK; ++g) {     // 36 steps, fully unrolled
        const int rho  = g / TPK;              // row index (static)
        const int tloc = g % TPK;              // K-step within slice (static)
        f32x4 u = qa[g % DEPTH], v = qb[g % DEPTH];
        if (g + DEPTH < NROW * TPK) {          // issue row rho+1 during rho
            const int gn = g + DEPTH;
            qa[g % DEPTH] = rp[gn / TPK][8 * (gn % TPK)];
            qb[g % DEPTH] = rp[gn / TPK][8 * (gn % TPK) + 1];
        }
        // exact 2-term f16 split of the 8 A floats (shared by all consumers)
        f16x8 ah, al;
        #pragma unroll
        for (int e = 0; e < 8; ++e) {
            float f = (e < 4) ? u[e] : v[e - 4];
            _Float16 hh = (_Float16)f;         // RTN
            ah[e] = hh;
            al[e] = (_Float16)(f - (float)hh); // exact residual -> f16
        }
        if (rv[rho]) {                         // block-uniform edge skip
            #pragma unroll
            for (int sv = 0; sv < QS; ++sv) {  // consumers: band w = rho-sv
                const int w = rho - sv;
                if (w < 0 || w > 2) continue;  // static prune after unroll
                const f16x8 bw = *(const f16x8*)
                    &wf[bidx + sv * 13824 + 4608 * w + 192 * tloc];
                acc_h[sv] = __builtin_amdgcn_mfma_f32_16x16x32_f16(
                                ah, bw, acc_h[sv], 0, 0, 0);
                acc_l[sv] = __builtin_amdgcn_mfma_f32_16x16x32_f16(
                                al, bw, acc_l[sv], 0, 0, 0);
            }
        }
        if (tloc == TPK - 1) __syncthreads();  // row-end L2 alignment
    }

    // ---- K-split-4 merge (3-round LDS tree), then bias+relu+store ----
    float tot[QS][4];
    #pragma unroll
    for (int sv = 0; sv < QS; ++sv)
        #pragma unroll
        for (int gg = 0; gg < 4; ++gg)
            tot[sv][gg] = acc_h[sv][gg] + acc_l[sv][gg];

    if (kv == 1 || kv == 3) {
        float* rb = red[kv >> 1];
        #pragma unroll
        for (int sv = 0; sv < QS; ++sv)
            #pragma unroll
            for (int gg = 0; gg < 4; ++gg)
                rb[((mt * QS + sv) * 4 + gg) * 64 + lane] = tot[sv][gg];
    }
    __syncthreads();
    if (kv == 0 || kv == 2) {
        const float* rb = red[kv >> 1];
        #pragma unroll
        for (int sv = 0; sv < QS; ++sv)
            #pragma unroll
            for (int gg = 0; gg < 4; ++gg)
                tot[sv][gg] += rb[((mt * QS + sv) * 4 + gg) * 64 + lane];
    }
    __syncthreads();
    if (kv == 2) {
        #pragma unroll
        for (int sv = 0; sv < QS; ++sv)
            #pragma unroll
            for (int gg = 0; gg < 4; ++gg)
                red[0][((mt * QS + sv) * 4 + gg) * 64 + lane] = tot[sv][gg];
    }
    __syncthreads();
    // C/D: col = lane&15, row(batch) = 4*(lane>>4) + gg  [HW-verified]
    if (kv == 0 && cv) {
        #pragma unroll
        for (int sv = 0; sv < QS; ++sv) {
            const float bv = bias[(s0 + sv) * FILT + col];
            #pragma unroll
            for (int gg = 0; gg < 4; ++gg) {
                const int b = b0 + 4 * h + gg;
                float val = tot[sv][gg] +
                            red[0][((mt * QS + sv) * 4 + gg) * 64 + lane] + bv;
                val = val > 0.f ? val : 0.f;
                out[((size_t)b * SEQ + (s0 + sv)) * FILT + col] = val;
            }
        }
    }
}

extern "C" void kernel_launch(void* const* d_in, const int* in_sizes, int n_in,
                              void* d_out, int out_size, void* d_ws, size_t ws_size,
                              hipStream_t stream) {
    const float* x   = (const float*)d_in[0];  // (256, 256, 768) fp32
    const float* W   = (const float*)d_in[1];  // (256, 2304, 6) fp32
    const float* b   = (const float*)d_in[2];  // (256, 6) fp32
    float*       out = (float*)d_out;          // (256, 256, 6) fp32
    (void)in_sizes; (void)n_in; (void)out_size; (void)d_ws; (void)ws_size;
    pos_linear_kernel<<<256, 1024, 0, stream>>>(x, W, b, out);
}